// Round 14
// baseline (144.312 us; speedup 1.0000x reference)
//
#include <hip/hip_runtime.h>
#include <hip/hip_fp16.h>

// BackProjectionLinear: out[b,p] = sum_d apod[d] * lerp(sino[b,d], k[p,d], a[p,d]) / 63.5
// B=4, N_DET=128, N_T=2048, pixels=65536.
//
// R14: R13 falsified the lut-stream theory (FETCH 66->41MB, dur unchanged).
// Unifying model for the 43-50us invariant: per-CU L1/TA divergent-line
// service rate (~0.3 lines/cyc). R13 burned ~37K line-misses/CU (global
// gathers: 64 distinct lines per wave instr). Fix: move random access back
// to the LDS pipe, but with ONE barrier and a free-running px loop:
//  - Block = 4 dets (quad) x 4096 px, 1024 thr. LDS = 4 dets x 2048 t x
//    uint2 (4 batches fp16) = 64KB, staged ONCE (coalesced uint4 copy).
//  - After the single barrier: 4 px-iterations, no syncs -- waves free-run,
//    lut misses of one wave overlap LDS gathers of another.
//  - Per-CU line-misses: lut ~8K (32B per quad-block; 2nd touch of each 64B
//    line L3-absorbed, cf R13 FETCH=41MB) + stage ~2K = ~10K vs R13's 37K.
//  - ws16 pre-pack kept (R10). Atomic emit kept (R9: atomics not a limiter;
//    8.4M atomics here).
//  - launch_bounds(1024,4): 128-VGPR cap, NO forcing to 64 (R7 spill trap);
//    compiler lands ~40-60 naturally -> 2 blocks/CU (LDS-bound), 32 waves.

#define NB      4
#define NDET    128
#define NT      2048
#define NPIX    65536
#define QDET    4                    // dets per block
#define THREADS 1024
#define PXTILE  4096
#define ITERS   (PXTILE / THREADS)   // 4

// ---- pass 1: sino fp32[4][128][2048] -> ws16[det][t] = (h0,h1,h2,h3) 8B ----
__global__ __launch_bounds__(256)
void cvt_kernel(const float* __restrict__ sino, uint2* __restrict__ ws16) {
    const int id = blockIdx.x * 256 + threadIdx.x;     // det*NT + t
    float v0 = sino[id];
    float v1 = sino[id + NDET * NT];
    float v2 = sino[id + 2 * NDET * NT];
    float v3 = sino[id + 3 * NDET * NT];
    __half2 h01 = __floats2half2_rn(v0, v1);
    __half2 h23 = __floats2half2_rn(v2, v3);
    uint2 u;
    u.x = *(const unsigned*)&h01;
    u.y = *(const unsigned*)&h23;
    ws16[id] = u;
}

__global__ __launch_bounds__(THREADS, 4)
void bp_kernel(const uint2* __restrict__ ws16,
               const float* __restrict__ lut,
               float* __restrict__ out) {
    // [dl (0..3)][t] : 8B = 4 batches fp16. 64 KB, staged once.
    __shared__ uint2 lds2[QDET * NT];

    const int tid  = threadIdx.x;
    const int quad = blockIdx.x & 31;    // 32 det-quads
    const int tile = blockIdx.x >> 5;    // 16 px tiles
    const int d0   = quad * QDET;
    const int px0  = tile * PXTILE;

    float apod[QDET];
#pragma unroll
    for (int j = 0; j < QDET; ++j) {
        float x = (float)(d0 + j) * (6.28318530717958647692f / 127.0f);
        apod[j] = 0.5f - 0.5f * __cosf(x);
    }

    // ---- stage the quad's 4 det rows once: 64KB coalesced copy ----
    {
        const uint4* src = (const uint4*)(ws16 + (size_t)d0 * NT);
        uint4* dst = (uint4*)lds2;
#pragma unroll
        for (int r = 0; r < (QDET * NT / 2) / THREADS; ++r)   // 4 iters
            dst[tid + r * THREADS] = src[tid + r * THREADS];
    }
    __syncthreads();                     // the ONLY barrier

    const float inv_norm = 1.0f / 63.5f; // sum(apod) == 63.5 exactly

    for (int it = 0; it < ITERS; ++it) {
        const int px = px0 + it * THREADS + tid;
        // this block's 32B of the pixel's lut line (2 float4)
        const float4* lp = (const float4*)(lut + ((size_t)px * NDET + d0) * 2);
        float4 L0 = lp[0];
        float4 L1 = lp[1];

        float acc[NB] = {0.0f, 0.0f, 0.0f, 0.0f};
#pragma unroll
        for (int q = 0; q < 2; ++q) {
            float4 Lq = q ? L1 : L0;
#pragma unroll
            for (int h = 0; h < 2; ++h) {
                int   j  = q * 2 + h;
                float kf = h ? Lq.z : Lq.x;
                float af = h ? Lq.w : Lq.y;
                int k = (int)kf;
                bool valid = (unsigned)k < (unsigned)(NT - 1);
                float w  = valid ? apod[j] : 0.0f;
                int  k0  = valid ? k : 0;
                uint2 e0 = lds2[j * NT + k0];
                uint2 e1 = lds2[j * NT + k0 + 1];
                __half2 a01 = *(__half2*)&e0.x, a23 = *(__half2*)&e0.y;
                __half2 b01 = *(__half2*)&e1.x, b23 = *(__half2*)&e1.y;
                __half2 a2  = __float2half2_rn(af);
                __half2 s01 = __hfma2(a2, __hsub2(b01, a01), a01);
                __half2 s23 = __hfma2(a2, __hsub2(b23, a23), a23);
                float2 f01 = __half22float2(s01);
                float2 f23 = __half22float2(s23);
                acc[0] = fmaf(w, f01.x, acc[0]);
                acc[1] = fmaf(w, f01.y, acc[1]);
                acc[2] = fmaf(w, f23.x, acc[2]);
                acc[3] = fmaf(w, f23.y, acc[3]);
            }
        }
#pragma unroll
        for (int b = 0; b < NB; ++b)
            atomicAdd(&out[(size_t)b * NPIX + px], acc[b] * inv_norm);
    }
}

// ---- fallback (ws too small): R8-style LDS kernel on raw sino ----
__global__ __launch_bounds__(512, 4)
void bp_fallback(const float* __restrict__ sino,
                 const float* __restrict__ lut,
                 float* __restrict__ out) {
    __shared__ __half2 lds[4][NT];
    const int tid   = threadIdx.x;
    const int octet = blockIdx.x & 15;
    const int tile  = blockIdx.x >> 4;
    const int d0    = octet * 8;
    const int px0   = tile * 1024;
    float apod[8];
#pragma unroll
    for (int j = 0; j < 8; ++j) {
        float x = (float)(d0 + j) * (6.28318530717958647692f / 127.0f);
        apod[j] = 0.5f - 0.5f * __cosf(x);
    }
    float4 L[2][4];
#pragma unroll
    for (int i = 0; i < 2; ++i) {
        const float4* lq = (const float4*)
            (lut + ((size_t)(px0 + tid + i * 512) * NDET + d0) * 2);
#pragma unroll
        for (int q = 0; q < 4; ++q) L[i][q] = lq[q];
    }
    float acc[2][NB];
#pragma unroll
    for (int i = 0; i < 2; ++i)
#pragma unroll
        for (int b = 0; b < NB; ++b) acc[i][b] = 0.0f;
    const float4* s4 = (const float4*)sino;
    for (int ph = 0; ph < 4; ++ph) {
        const int b0  = (ph >> 1) * 2;
        const int dh  = ph & 1;
        const int dg0 = d0 + dh * 4;
        if (ph) __syncthreads();
        for (int f = tid; f < 4 * (NT / 4); f += 512) {
            int dl = f >> 9;
            int t4 = f & 511;
            size_t row = ((size_t)b0 * NDET + dg0 + dl) * (NT / 4) + t4;
            float4 ve = s4[row];
            float4 vo = s4[row + (size_t)NDET * (NT / 4)];
            __half2* dstp = &lds[dl][t4 * 4];
            dstp[0] = __floats2half2_rn(ve.x, vo.x);
            dstp[1] = __floats2half2_rn(ve.y, vo.y);
            dstp[2] = __floats2half2_rn(ve.z, vo.z);
            dstp[3] = __floats2half2_rn(ve.w, vo.w);
        }
        __syncthreads();
#pragma unroll
        for (int i = 0; i < 2; ++i) {
#pragma unroll
            for (int q2 = 0; q2 < 2; ++q2) {
                float4 Lq = L[i][dh * 2 + q2];
#pragma unroll
                for (int h = 0; h < 2; ++h) {
                    float kf = h ? Lq.z : Lq.x;
                    float af = h ? Lq.w : Lq.y;
                    int   dl = q2 * 2 + h;
                    int k = (int)kf;
                    bool valid = (unsigned)k < (unsigned)(NT - 1);
                    float w  = valid ? apod[dh * 4 + dl] : 0.0f;
                    int  k0  = valid ? k : 0;
                    __half2 s0v = lds[dl][k0];
                    __half2 s1v = lds[dl][k0 + 1];
                    __half2 a2  = __float2half2_rn(af);
                    __half2 sk  = __hfma2(a2, __hsub2(s1v, s0v), s0v);
                    float2  fv  = __half22float2(sk);
                    acc[i][b0 + 0] = fmaf(w, fv.x, acc[i][b0 + 0]);
                    acc[i][b0 + 1] = fmaf(w, fv.y, acc[i][b0 + 1]);
                }
            }
        }
    }
    const float inv_norm = 1.0f / 63.5f;
#pragma unroll
    for (int i = 0; i < 2; ++i) {
        const int px = px0 + tid + i * 512;
#pragma unroll
        for (int b = 0; b < NB; ++b)
            atomicAdd(&out[(size_t)b * NPIX + px], acc[i][b] * inv_norm);
    }
}

extern "C" void kernel_launch(void* const* d_in, const int* in_sizes, int n_in,
                              void* d_out, int out_size, void* d_ws, size_t ws_size,
                              hipStream_t stream) {
    const float* sino = (const float*)d_in[0];
    const float* lut  = (const float*)d_in[1];
    float* out = (float*)d_out;

    (void)hipMemsetAsync(d_out, 0, (size_t)out_size * sizeof(float), stream);

    const size_t ws_needed = (size_t)NDET * NT * sizeof(uint2);   // 2 MB
    if (ws_size >= ws_needed) {
        uint2* ws16 = (uint2*)d_ws;
        cvt_kernel<<<dim3(NDET * NT / 256), dim3(256), 0, stream>>>(sino, ws16);
        // 32 quads x 16 px-tiles = 512 blocks x 1024 thr, 64KB LDS,
        // one barrier per block, then free-running px loop.
        bp_kernel<<<dim3(512), dim3(THREADS), 0, stream>>>(ws16, lut, out);
    } else {
        bp_fallback<<<dim3(1024), dim3(512), 0, stream>>>(sino, lut, out);
    }
}